// Round 9
// baseline (241.119 us; speedup 1.0000x reference)
//
#include <hip/hip_runtime.h>
#include <cmath>

// Problem constants (from reference)
constexpr int B_ = 2, NCLS = 3, A_ = 3, D_ = 96, H_ = 96, W_ = 96, K_ = 128;
constexpr int CH = NCLS * A_;          // 9 channels in cls_logit
constexpr int HW = H_ * W_;            // 9216
constexpr int SPAT = D_ * HW;          // 884736
constexpr float EPS_ = 1e-4f;
constexpr float BETA_ = 1.0f / 9.0f;

// Wave-task decomposition: 64 lanes = 4 h-rows x 16 w-segments, 6 w per lane;
// one task = (b, c, h-group of 4, d-chunk of 6). Each WAVE interleaves TWO
// consecutive tasks (adjacent d-chunks of the same (b,c,hg)) for 2x MLP.
constexpr int WPL = 6;                 // w per lane
constexpr int DCHUNK = 6;
constexpr int NDC = D_ / DCHUNK;       // 16
constexpr int HGRP = 4;
constexpr int NHG = H_ / HGRP;         // 24
constexpr int NTASK = B_ * CH * NHG * NDC;   // 6912 tasks
constexpr int NW = NTASK / 2;                // 3456 waves (2 tasks each)
constexpr int NBLK = NW / 4;                 // 864 blocks x 256 threads

static __device__ __forceinline__ float sigmoid_clip(float x) {
  float s = 1.0f / (1.0f + __expf(-x));
  return fminf(fmaxf(s, EPS_), 1.0f - EPS_);
}

static __device__ __forceinline__ void load6(const float* __restrict__ p,
                                             float* f) {
  const float2 u0 = *(const float2*)(p);
  const float2 u1 = *(const float2*)(p + 2);
  const float2 u2 = *(const float2*)(p + 4);
  f[0] = u0.x; f[1] = u0.y; f[2] = u1.x;
  f[3] = u1.y; f[4] = u2.x; f[5] = u2.y;
}

// ------- Kernel 1: negative focal loss, register sliding-window max ---------
// Two independent tiles per wave, register-interleaved (ILP-2), depth-1
// prefetch per tile. Writes per-wave partials to ws[wid] / ws[NW+wid].
__global__ __launch_bounds__(256) void neg_loss_kernel(
    const float* __restrict__ x, const float* __restrict__ pgt,
    float* __restrict__ ws) {
  const int tid = threadIdx.x;
  const int lane = tid & 63;
  const int wid = blockIdx.x * 4 + (tid >> 6);  // wave id in [0, NW)

  const int hl = lane >> 4;              // h within group: 0..3
  const int wseg = lane & 15;            // w segment: 0..15
  const int w0 = wseg * WPL;
  const int wm = (wseg == 0);            // clamp flags
  const int wq = (wseg == 15);

  // tasks t = wid*2 + j, j in {0,1}; consecutive dci of same (hg,c,b)
  int tt = wid * 2;
  const int dci0 = tt % NDC; tt /= NDC;
  const int hg = tt % NHG; tt /= NHG;
  const int c = tt % CH;
  const int b = tt / CH;
  const int h = hg * HGRP + hl;
  const int a = c - (c / A_) * A_;       // c % 3

  const float* base = x + (size_t)(b * CH + c) * SPAT;
  const int hm = max(h - 1, 0), hq = min(h + 1, H_ - 1);
  const float* rowm = base + hm * W_ + w0;
  const float* rowc = base + h * W_ + w0;
  const float* rowp = base + hq * W_ + w0;
  const float* pgb = pgt + (size_t)(b * A_ + a) * SPAT + h * W_ + w0;

  int d0[2];
  d0[0] = dci0 * DCHUNK;
  d0[1] = d0[0] + DCHUNK;                // dci0 is even; task 1 is next chunk

  float sprev[2][6], scur[2][6], ccur[2][6];
  float nm[2][6], nc[2][6], np[2][6];    // prefetched x plane d+1 (raw rows)
  float pgv[2][6];                       // prefetched pg plane d

#pragma unroll
  for (int j = 0; j < 2; ++j) {
    float fm[6], fc[6], fp[6], gm[6], gc[6], gp[6];
    const int plm = max(d0[j] - 1, 0) * HW;
    load6(rowm + plm, fm); load6(rowc + plm, fc); load6(rowp + plm, fp);
    const int pl0 = d0[j] * HW;
    load6(rowm + pl0, gm); load6(rowc + pl0, gc); load6(rowp + pl0, gp);
    const int pl1 = min(d0[j] + 1, D_ - 1) * HW;
    load6(rowm + pl1, nm[j]); load6(rowc + pl1, nc[j]);
    load6(rowp + pl1, np[j]);
    load6(pgb + pl0, pgv[j]);
#pragma unroll
    for (int i = 0; i < 6; ++i) {
      sprev[j][i] = fmaxf(fmaxf(fm[i], fc[i]), fp[i]);
      scur[j][i] = fmaxf(fmaxf(gm[i], gc[i]), gp[i]);
      ccur[j][i] = gc[i];
    }
  }

  float lsum = 0.0f, csum = 0.0f;
#pragma unroll
  for (int k = 0; k < DCHUNK; ++k) {
#pragma unroll
    for (int j = 0; j < 2; ++j) {
      const int d = d0[j] + k;
      // consume prefetched x plane d+1 and pg plane d (issued last iter)
      float snext[6], cnext[6], pgc[6];
#pragma unroll
      for (int i = 0; i < 6; ++i) {
        snext[i] = fmaxf(fmaxf(nm[j][i], nc[j][i]), np[j][i]);
        cnext[i] = nc[j][i];
        pgc[i] = pgv[j][i];
      }
      // issue prefetch for x plane d+2 and pg plane d+1
      const int pl2 = min(d + 2, D_ - 1) * HW;
      load6(rowm + pl2, nm[j]); load6(rowc + pl2, nc[j]);
      load6(rowp + pl2, np[j]);
      load6(pgb + min(d + 1, D_ - 1) * HW, pgv[j]);

      float cmx[6], m[6];
#pragma unroll
      for (int i = 0; i < 6; ++i)
        cmx[i] = fmaxf(fmaxf(sprev[j][i], scur[j][i]), snext[i]);
      // cross-segment halo via wave shuffles
      float left = __shfl_up(cmx[5], 1);
      float right = __shfl_down(cmx[0], 1);
      if (wm) left = cmx[0];             // w==0 clamps
      if (wq) right = cmx[5];            // w==95 clamps
      m[0] = fmaxf(left, fmaxf(cmx[0], cmx[1]));
      m[1] = fmaxf(cmx[0], fmaxf(cmx[1], cmx[2]));
      m[2] = fmaxf(cmx[1], fmaxf(cmx[2], cmx[3]));
      m[3] = fmaxf(cmx[2], fmaxf(cmx[3], cmx[4]));
      m[4] = fmaxf(cmx[3], fmaxf(cmx[4], cmx[5]));
      m[5] = fmaxf(cmx[4], fmaxf(cmx[5], right));

      // branchless accumulate
#pragma unroll
      for (int i = 0; i < 6; ++i) {
        const float prob = sigmoid_clip(ccur[j][i]);
        const bool pred =
            (m[i] == ccur[j][i]) && (pgc[i] == -1.0f) && (prob > EPS_);
        lsum += pred ? (-__logf(1.0f - prob) * prob) : 0.0f;
        csum += pred ? prob : 0.0f;
      }
#pragma unroll
      for (int i = 0; i < 6; ++i) {
        sprev[j][i] = scur[j][i]; scur[j][i] = snext[i]; ccur[j][i] = cnext[i];
      }
    }
  }

  // wave shuffle reduce; lane 0 writes per-wave partials (no atomics)
#pragma unroll
  for (int off = 32; off > 0; off >>= 1) {
    lsum += __shfl_down(lsum, off);
    csum += __shfl_down(csum, off);
  }
  if (lane == 0) {
    ws[wid] = lsum;
    ws[NW + wid] = csum;
  }
}

// ------ Kernel 2: K-point gathered terms + partial-sum reduce + output ------
__global__ __launch_bounds__(256) void small_kernel(
    const float* __restrict__ x, const float* __restrict__ rp,
    const float* __restrict__ pgt, const int* __restrict__ cprob,
    const int* __restrict__ cdiff, const float* __restrict__ dgt,
    const float* __restrict__ wcls, const float* __restrict__ ws,
    float* __restrict__ out) {
  const int tid = threadIdx.x;
  // v: l_pos, c_pos, l_oth, c_oth, l_reg, c_reg, l_neg, c_neg
  float v[8] = {0.f, 0.f, 0.f, 0.f, 0.f, 0.f, 0.f, 0.f};
  // reduce neg-loss per-wave partials (coalesced strided)
  for (int i = tid; i < NW; i += 256) {
    v[6] += ws[i];
    v[7] += ws[NW + i];
  }
  if (tid < B_ * K_) {
    const int b = tid / K_, k = tid - b * K_;
    {  // positive focal + other-class suppression
      const int* cp = cprob + (b * K_ + k) * 4;
      const int ca = cp[0];
      const float m = (ca > -1) ? 1.0f : 0.0f;
      const int a = max(ca, 0), d = max(cp[1], 0), h = max(cp[2], 0),
                ww = max(cp[3], 0);
      const int sp = (d * H_ + h) * W_ + ww;
      float po[NCLS];
#pragma unroll
      for (int c = 0; c < NCLS; ++c)
        po[c] = sigmoid_clip(x[(size_t)(b * CH + c * A_ + a) * SPAT + sp]);
      const float pg = pgt[(size_t)(b * A_ + a) * SPAT + sp];
      int cg = (int)pg - 1;  // astype(int32) truncation, then clip
      cg = min(max(cg, 0), NCLS - 1);
      const float pt = po[cg];
      const float wp = (1.0f - pt) * wcls[cg] * m;
      v[0] = -__logf(pt) * wp;
      v[1] = wp;
      const float ptgt = (pt > 0.5f) ? 1.0f : 0.0f;
#pragma unroll
      for (int c = 0; c < NCLS; ++c) {
        if (c == cg) continue;
        const float wo = fmaxf(po[c] - (pt - 0.1f), 0.0f) *
                         ((po[c] > 0.5f) ? 1.0f : 0.0f) * ptgt * m;
        v[2] += -__logf(1.0f - po[c]) * wo;
        v[3] += wo;
      }
    }
    {  // smooth-L1 regression
      const int* cd = cdiff + (b * K_ + k) * 4;
      const float md = (cd[0] > -1) ? 1.0f : 0.0f;
      const int a = max(cd[0], 0), d = max(cd[1], 0), h = max(cd[2], 0),
                ww = max(cd[3], 0);
      const int sp = (d * H_ + h) * W_ + ww;
#pragma unroll
      for (int j = 0; j < 6; ++j) {
        const float val = rp[(size_t)(b * 6 * A_ + j * A_ + a) * SPAT + sp];
        const float tgt = dgt[(b * K_ + k) * 6 + j];
        const float n = fabsf(val - tgt);
        const float s = (n < BETA_) ? (0.5f * n * n / BETA_) : (n - 0.5f * BETA_);
        v[4] += s * md;
      }
      v[5] = md;
    }
  }
  __shared__ float red[256][8];
#pragma unroll
  for (int j = 0; j < 8; ++j) red[tid][j] = v[j];
  __syncthreads();
  for (int s = 128; s > 0; s >>= 1) {
    if (tid < s) {
#pragma unroll
      for (int j = 0; j < 8; ++j) red[tid][j] += red[tid + s][j];
    }
    __syncthreads();
  }
  if (tid == 0) {
    const float l_pos = red[0][0], c_pos = red[0][1];
    const float l_oth = red[0][2], c_oth = red[0][3];
    const float l_reg = red[0][4], c_reg = red[0][5];
    const float l_neg = red[0][6], c_neg = red[0][7];
    out[0] = l_pos + l_neg + l_oth + l_reg;  // all lambdas = 1
    out[1] = l_pos;
    out[2] = l_neg;
    out[3] = l_oth;
    out[4] = l_reg;
    out[5] = c_pos;
    out[6] = c_neg;
    out[7] = c_oth;
    out[8] = c_reg;
  }
}

extern "C" void kernel_launch(void* const* d_in, const int* in_sizes, int n_in,
                              void* d_out, int out_size, void* d_ws,
                              size_t ws_size, hipStream_t stream) {
  const float* cls_logit = (const float*)d_in[0];
  const float* reg_pred = (const float*)d_in[1];
  const float* prob_gt = (const float*)d_in[2];
  const int* coord_prob = (const int*)d_in[3];
  const int* coord_diff = (const int*)d_in[4];
  const float* diff_gt = (const float*)d_in[5];
  const float* weight_cls = (const float*)d_in[6];
  float* out = (float*)d_out;
  float* ws = (float*)d_ws;  // [0..NW)=l_neg partials, [NW..2*NW)=count

  neg_loss_kernel<<<NBLK, 256, 0, stream>>>(cls_logit, prob_gt, ws);
  small_kernel<<<1, 256, 0, stream>>>(cls_logit, reg_pred, prob_gt, coord_prob,
                                      coord_diff, diff_gt, weight_cls, ws,
                                      out);
}

// Round 10
// 230.641 us; speedup vs baseline: 1.0454x; 1.0454x over previous
//
#include <hip/hip_runtime.h>
#include <cmath>

// Problem constants (from reference)
constexpr int B_ = 2, NCLS = 3, A_ = 3, D_ = 96, H_ = 96, W_ = 96, K_ = 128;
constexpr int CH = NCLS * A_;          // 9 channels in cls_logit
constexpr int HW = H_ * W_;            // 9216
constexpr int SPAT = D_ * HW;          // 884736
constexpr float EPS_ = 1e-4f;
constexpr float BETA_ = 1.0f / 9.0f;

// Wave-task decomposition: one wave (64 lanes = 4 h-rows x 16 w-segments,
// 6 w per lane) covers (b, c, h-group of 4, d-chunk of 6).
// Final structure (best measured: 231.9 µs total). Session ledger:
//   R1 naive per-voxel 27-tap: 260 µs kernel (VALU-instruction-bound)
//   R2 separable + LDS halo:   111 µs (barrier-latency-bound)
//   R3 register window + shfl:  83 µs
//   R4 prefetch x-planes:      ~60 µs
//   R5 prefetch pg + branchless: ~38 µs  <-- this kernel
//   R6 depth-2 pipeline: neutral; R7 fused single-kernel: -74 µs REGRESS;
//   R8 wave-per-block: +8 µs; R9 ILP-2 tiles: +9 µs.
// Remaining ~195 µs of timed 232 µs = harness re-poison fills at 85% HBM peak.
constexpr int WPL = 6;                 // w per lane
constexpr int DCHUNK = 6;
constexpr int NDC = D_ / DCHUNK;       // 16
constexpr int HGRP = 4;
constexpr int NHG = H_ / HGRP;         // 24
constexpr int NWAVES = B_ * CH * NHG * NDC;  // 6912
constexpr int NBLK = NWAVES / 4;             // 1728 blocks x 256 threads

static __device__ __forceinline__ float sigmoid_clip(float x) {
  float s = 1.0f / (1.0f + __expf(-x));
  return fminf(fmaxf(s, EPS_), 1.0f - EPS_);
}

static __device__ __forceinline__ void load6(const float* __restrict__ p,
                                             float* f) {
  const float2 u0 = *(const float2*)(p);
  const float2 u1 = *(const float2*)(p + 2);
  const float2 u2 = *(const float2*)(p + 4);
  f[0] = u0.x; f[1] = u0.y; f[2] = u1.x;
  f[3] = u1.y; f[4] = u2.x; f[5] = u2.y;
}

// ------- Kernel 1: negative focal loss, register sliding-window max ---------
// Depth-2 software pipeline: raw rows of planes d+1 and d+2 (and pg planes
// d, d+1) live in parity-alternated register buffers.
// Writes per-block partial sums to ws[blk] (l_neg) and ws[NBLK+blk] (count).
__global__ __launch_bounds__(256) void neg_loss_kernel(
    const float* __restrict__ x, const float* __restrict__ pgt,
    float* __restrict__ ws) {
  const int tid = threadIdx.x;
  const int lane = tid & 63;
  int t = blockIdx.x * 4 + (tid >> 6);   // wave-task id
  const int dci = t % NDC; t /= NDC;
  const int hg = t % NHG; t /= NHG;
  const int c = t % CH;
  const int b = t / CH;

  const int hl = lane >> 4;              // h within group: 0..3
  const int wseg = lane & 15;            // w segment: 0..15
  const int h = hg * HGRP + hl;
  const int w0 = wseg * WPL;
  const int d0 = dci * DCHUNK;
  const int a = c - (c / A_) * A_;       // c % 3

  const float* base = x + (size_t)(b * CH + c) * SPAT;
  const int hm = max(h - 1, 0), hq = min(h + 1, H_ - 1);
  const float* rowm = base + hm * W_ + w0;
  const float* rowc = base + h * W_ + w0;
  const float* rowp = base + hq * W_ + w0;
  const float* pgb = pgt + (size_t)(b * A_ + a) * SPAT + h * W_ + w0;

  float sprev[6], scur[6], ccur[6];
  float bufm[2][6], bufc[2][6], bufp[2][6];  // raw x rows: planes d+1, d+2
  float pgbuf[2][6];                         // pg planes d, d+1
  {
    float fm[6], fc[6], fp[6], gm[6], gc[6], gp[6];
    const int plm = max(d0 - 1, 0) * HW;
    load6(rowm + plm, fm); load6(rowc + plm, fc); load6(rowp + plm, fp);
    const int pl0 = d0 * HW;
    load6(rowm + pl0, gm); load6(rowc + pl0, gc); load6(rowp + pl0, gp);
    const int pl1 = (d0 + 1) * HW;             // d0+1 <= 91, no clamp needed
    load6(rowm + pl1, bufm[0]); load6(rowc + pl1, bufc[0]);
    load6(rowp + pl1, bufp[0]);
    const int pl2 = (d0 + 2) * HW;             // d0+2 <= 92
    load6(rowm + pl2, bufm[1]); load6(rowc + pl2, bufc[1]);
    load6(rowp + pl2, bufp[1]);
    load6(pgb + pl0, pgbuf[0]);
    load6(pgb + pl1, pgbuf[1]);
#pragma unroll
    for (int i = 0; i < 6; ++i) sprev[i] = fmaxf(fmaxf(fm[i], fc[i]), fp[i]);
#pragma unroll
    for (int i = 0; i < 6; ++i) {
      scur[i] = fmaxf(fmaxf(gm[i], gc[i]), gp[i]);
      ccur[i] = gc[i];
    }
  }

  float lsum = 0.0f, csum = 0.0f;
#pragma unroll
  for (int k = 0; k < DCHUNK; ++k) {
    const int d = d0 + k;
    const int par = k & 1;
    // consume buffers filled two iterations ago (prologue for k=0,1)
    float snext[6], cnext[6], pgc[6];
#pragma unroll
    for (int i = 0; i < 6; ++i) {
      snext[i] = fmaxf(fmaxf(bufm[par][i], bufc[par][i]), bufp[par][i]);
      cnext[i] = bufc[par][i];
      pgc[i] = pgbuf[par][i];
    }
    // refill: x plane d+3 and pg plane d+2 (consumed at iteration k+2)
    const int pl3 = min(d + 3, D_ - 1) * HW;
    load6(rowm + pl3, bufm[par]); load6(rowc + pl3, bufc[par]);
    load6(rowp + pl3, bufp[par]);
    load6(pgb + min(d + 2, D_ - 1) * HW, pgbuf[par]);

    float cmx[6], m[6];
#pragma unroll
    for (int i = 0; i < 6; ++i)
      cmx[i] = fmaxf(fmaxf(sprev[i], scur[i]), snext[i]);
    // cross-segment halo via wave shuffles (same h-row for wseg>0 / wseg<15)
    float left = __shfl_up(cmx[5], 1);
    float right = __shfl_down(cmx[0], 1);
    if (wseg == 0) left = cmx[0];      // w==0 clamps
    if (wseg == 15) right = cmx[5];    // w==95 clamps
    m[0] = fmaxf(left, fmaxf(cmx[0], cmx[1]));
    m[1] = fmaxf(cmx[0], fmaxf(cmx[1], cmx[2]));
    m[2] = fmaxf(cmx[1], fmaxf(cmx[2], cmx[3]));
    m[3] = fmaxf(cmx[2], fmaxf(cmx[3], cmx[4]));
    m[4] = fmaxf(cmx[3], fmaxf(cmx[4], cmx[5]));
    m[5] = fmaxf(cmx[4], fmaxf(cmx[5], right));

    // branchless accumulate: no memory dependency in the predicate path
#pragma unroll
    for (int i = 0; i < 6; ++i) {
      const float prob = sigmoid_clip(ccur[i]);
      const bool pred =
          (m[i] == ccur[i]) && (pgc[i] == -1.0f) && (prob > EPS_);
      lsum += pred ? (-__logf(1.0f - prob) * prob) : 0.0f;
      csum += pred ? prob : 0.0f;
    }
#pragma unroll
    for (int i = 0; i < 6; ++i) {
      sprev[i] = scur[i]; scur[i] = snext[i]; ccur[i] = cnext[i];
    }
  }

  // wave shuffle reduce then cross-wave via LDS; per-block partial to ws
#pragma unroll
  for (int off = 32; off > 0; off >>= 1) {
    lsum += __shfl_down(lsum, off);
    csum += __shfl_down(csum, off);
  }
  __shared__ float sl[4], sc[4];
  const int wv = tid >> 6;
  if (lane == 0) { sl[wv] = lsum; sc[wv] = csum; }
  __syncthreads();
  if (tid == 0) {
    ws[blockIdx.x] = sl[0] + sl[1] + sl[2] + sl[3];
    ws[NBLK + blockIdx.x] = sc[0] + sc[1] + sc[2] + sc[3];
  }
}

// ------ Kernel 2: K-point gathered terms + partial-sum reduce + output ------
__global__ __launch_bounds__(256) void small_kernel(
    const float* __restrict__ x, const float* __restrict__ rp,
    const float* __restrict__ pgt, const int* __restrict__ cprob,
    const int* __restrict__ cdiff, const float* __restrict__ dgt,
    const float* __restrict__ wcls, const float* __restrict__ ws,
    float* __restrict__ out) {
  const int tid = threadIdx.x;
  // v: l_pos, c_pos, l_oth, c_oth, l_reg, c_reg, l_neg, c_neg
  float v[8] = {0.f, 0.f, 0.f, 0.f, 0.f, 0.f, 0.f, 0.f};
  // reduce neg-loss per-block partials (coalesced strided)
  for (int i = tid; i < NBLK; i += 256) {
    v[6] += ws[i];
    v[7] += ws[NBLK + i];
  }
  if (tid < B_ * K_) {
    const int b = tid / K_, k = tid - b * K_;
    {  // positive focal + other-class suppression
      const int* cp = cprob + (b * K_ + k) * 4;
      const int ca = cp[0];
      const float m = (ca > -1) ? 1.0f : 0.0f;
      const int a = max(ca, 0), d = max(cp[1], 0), h = max(cp[2], 0),
                ww = max(cp[3], 0);
      const int sp = (d * H_ + h) * W_ + ww;
      float po[NCLS];
#pragma unroll
      for (int c = 0; c < NCLS; ++c)
        po[c] = sigmoid_clip(x[(size_t)(b * CH + c * A_ + a) * SPAT + sp]);
      const float pg = pgt[(size_t)(b * A_ + a) * SPAT + sp];
      int cg = (int)pg - 1;  // astype(int32) truncation, then clip
      cg = min(max(cg, 0), NCLS - 1);
      const float pt = po[cg];
      const float wp = (1.0f - pt) * wcls[cg] * m;
      v[0] = -__logf(pt) * wp;
      v[1] = wp;
      const float ptgt = (pt > 0.5f) ? 1.0f : 0.0f;
#pragma unroll
      for (int c = 0; c < NCLS; ++c) {
        if (c == cg) continue;
        const float wo = fmaxf(po[c] - (pt - 0.1f), 0.0f) *
                         ((po[c] > 0.5f) ? 1.0f : 0.0f) * ptgt * m;
        v[2] += -__logf(1.0f - po[c]) * wo;
        v[3] += wo;
      }
    }
    {  // smooth-L1 regression
      const int* cd = cdiff + (b * K_ + k) * 4;
      const float md = (cd[0] > -1) ? 1.0f : 0.0f;
      const int a = max(cd[0], 0), d = max(cd[1], 0), h = max(cd[2], 0),
                ww = max(cd[3], 0);
      const int sp = (d * H_ + h) * W_ + ww;
#pragma unroll
      for (int j = 0; j < 6; ++j) {
        const float val = rp[(size_t)(b * 6 * A_ + j * A_ + a) * SPAT + sp];
        const float tgt = dgt[(b * K_ + k) * 6 + j];
        const float n = fabsf(val - tgt);
        const float s = (n < BETA_) ? (0.5f * n * n / BETA_) : (n - 0.5f * BETA_);
        v[4] += s * md;
      }
      v[5] = md;
    }
  }
  __shared__ float red[256][8];
#pragma unroll
  for (int j = 0; j < 8; ++j) red[tid][j] = v[j];
  __syncthreads();
  for (int s = 128; s > 0; s >>= 1) {
    if (tid < s) {
#pragma unroll
      for (int j = 0; j < 8; ++j) red[tid][j] += red[tid + s][j];
    }
    __syncthreads();
  }
  if (tid == 0) {
    const float l_pos = red[0][0], c_pos = red[0][1];
    const float l_oth = red[0][2], c_oth = red[0][3];
    const float l_reg = red[0][4], c_reg = red[0][5];
    const float l_neg = red[0][6], c_neg = red[0][7];
    out[0] = l_pos + l_neg + l_oth + l_reg;  // all lambdas = 1
    out[1] = l_pos;
    out[2] = l_neg;
    out[3] = l_oth;
    out[4] = l_reg;
    out[5] = c_pos;
    out[6] = c_neg;
    out[7] = c_oth;
    out[8] = c_reg;
  }
}

extern "C" void kernel_launch(void* const* d_in, const int* in_sizes, int n_in,
                              void* d_out, int out_size, void* d_ws,
                              size_t ws_size, hipStream_t stream) {
  const float* cls_logit = (const float*)d_in[0];
  const float* reg_pred = (const float*)d_in[1];
  const float* prob_gt = (const float*)d_in[2];
  const int* coord_prob = (const int*)d_in[3];
  const int* coord_diff = (const int*)d_in[4];
  const float* diff_gt = (const float*)d_in[5];
  const float* weight_cls = (const float*)d_in[6];
  float* out = (float*)d_out;
  float* ws = (float*)d_ws;  // [0..NBLK)=l_neg partials, [NBLK..2*NBLK)=count

  neg_loss_kernel<<<NBLK, 256, 0, stream>>>(cls_logit, prob_gt, ws);
  small_kernel<<<1, 256, 0, stream>>>(cls_logit, reg_pred, prob_gt, coord_prob,
                                      coord_diff, diff_gt, weight_cls, ws,
                                      out);
}